// Round 1
// baseline (740.191 us; speedup 1.0000x reference)
//
#include <hip/hip_runtime.h>

// GroupedQueryAttention: B=1, S=2048, D_IN=D_OUT=4096, NH=32, NKV=8, HD=128, causal.
// Pipeline: cast->bf16, fused QKV GEMM (MFMA), RoPE, flash attention (MFMA), out GEMM.

typedef __bf16 bf16;
typedef __bf16 bf16x4 __attribute__((ext_vector_type(4)));
typedef __bf16 bf16x8 __attribute__((ext_vector_type(8)));
typedef float  f32x4  __attribute__((ext_vector_type(4)));

#define S_LEN   2048
#define DMODEL  4096
#define QKV_N   6144      // 4096 Q + 1024 K + 1024 V
#define K_OFF   4096
#define V_OFF   5120
#define HD      128
#define ATT_SCALE 0.08838834764831845f  // 1/sqrt(128)

// async global->LDS, 16B per lane; LDS dest must be wave-uniform (HW: base + lane*16)
__device__ __forceinline__ void gload16(const bf16* g, bf16* l) {
    __builtin_amdgcn_global_load_lds(
        (__attribute__((address_space(1))) void*)(g),
        (__attribute__((address_space(3))) void*)(l),
        16, 0, 0);
}

// ---------------- cast fp32 -> bf16, float4 vectorized ----------------
__global__ __launch_bounds__(256) void cast_f32_bf16(const float* __restrict__ in,
                                                     bf16* __restrict__ out, int n4) {
    int i = blockIdx.x * 256 + threadIdx.x;
    if (i >= n4) return;
    float4 v = reinterpret_cast<const float4*>(in)[i];
    bf16x4 o;
    o[0] = (bf16)v.x; o[1] = (bf16)v.y; o[2] = (bf16)v.z; o[3] = (bf16)v.w;
    reinterpret_cast<bf16x4*>(out)[i] = o;
}

// ---------------- GEMM: C[M,N] = A[M,K] * B[N,K]^T  (both row-major, K contig) ------
// m97 structure: 128x128 tile, BK=32, 4 waves, each wave 64x64 (4x4 of 16x16x32 MFMA)
template <typename OutT>
__global__ __launch_bounds__(256) void gemm_bt(const bf16* __restrict__ A,
                                               const bf16* __restrict__ B,
                                               OutT* __restrict__ C,
                                               int M, int N, int K, int ldc) {
    __shared__ bf16 As[128 * 32];
    __shared__ bf16 Bs[128 * 32];
    const int t    = threadIdx.x;
    const int wave = t >> 6, lane = t & 63;
    const int quad = lane >> 4, l15 = lane & 15;
    const int wm = (wave >> 1) * 64, wn = (wave & 1) * 64;
    const int bm = blockIdx.y * 128, bn = blockIdx.x * 128;

    f32x4 acc[4][4];
#pragma unroll
    for (int i = 0; i < 4; ++i)
#pragma unroll
        for (int j = 0; j < 4; ++j) acc[i][j] = (f32x4){0.f, 0.f, 0.f, 0.f};

    const int soff  = t * 8;            // element offset within 2048-elem chunk
    const int arow0 = soff >> 5;        // row within 64-row half tile
    const int acol  = soff & 31;

    for (int k0 = 0; k0 < K; k0 += 32) {
        __syncthreads();
#pragma unroll
        for (int it = 0; it < 2; ++it) {
            gload16(A + (size_t)(bm + arow0 + it * 64) * K + k0 + acol,
                    As + it * 2048 + wave * 512);
            gload16(B + (size_t)(bn + arow0 + it * 64) * K + k0 + acol,
                    Bs + it * 2048 + wave * 512);
        }
        __syncthreads();

        bf16x8 af[4], bfb[4];
#pragma unroll
        for (int i = 0; i < 4; ++i)
            af[i] = *reinterpret_cast<const bf16x8*>(&As[(wm + i * 16 + l15) * 32 + quad * 8]);
#pragma unroll
        for (int j = 0; j < 4; ++j)
            bfb[j] = *reinterpret_cast<const bf16x8*>(&Bs[(wn + j * 16 + l15) * 32 + quad * 8]);
#pragma unroll
        for (int i = 0; i < 4; ++i)
#pragma unroll
            for (int j = 0; j < 4; ++j)
                acc[i][j] = __builtin_amdgcn_mfma_f32_16x16x32_bf16(af[i], bfb[j], acc[i][j], 0, 0, 0);
    }

    // C/D layout: col = lane&15, row = quad*4 + reg  (HW-verified)
#pragma unroll
    for (int i = 0; i < 4; ++i) {
        const int m0 = bm + wm + i * 16 + quad * 4;
#pragma unroll
        for (int j = 0; j < 4; ++j) {
            const int n = bn + wn + j * 16 + l15;
#pragma unroll
            for (int r = 0; r < 4; ++r)
                C[(size_t)(m0 + r) * ldc + n] = (OutT)acc[i][j][r];
        }
    }
}

// ---------------- RoPE on Q (32 heads) + K (8 heads) in the fused QKV buffer --------
__global__ __launch_bounds__(256) void rope_kernel(bf16* __restrict__ qkv,
                                                   const float* __restrict__ cosT,
                                                   const float* __restrict__ sinT) {
    const int col = blockIdx.x * 256 + threadIdx.x;  // 0 .. 40*64-1
    if (col >= 40 * 64) return;
    const int row  = blockIdx.y;
    const int head = col >> 6, d = col & 63;
    const size_t base = (size_t)row * QKV_N + head * 128 + d;
    const float x1 = (float)qkv[base];
    const float x2 = (float)qkv[base + 64];
    const float c  = cosT[row * 128 + d];   // table halves are identical
    const float s  = sinT[row * 128 + d];
    qkv[base]      = (bf16)(x1 * c - x2 * s);
    qkv[base + 64] = (bf16)(x2 * c + x1 * s);
}

// ---------------- flash attention, causal, GQA group=4 ----------------
// block: 256 thr = 4 waves; BQ=64 (16 q-rows/wave), BKV=64, HD=128.
// Ks LDS layout: chunk-plane  Ks[cd][n][8]  (cd = d-chunk 0..15, n = kv row 0..63)
//   -> ds_read_b128 conflict-free; still global_load_lds compatible.
// Vt LDS: transposed [d][n] with row stride 72 (pad) for conflict-free b128 reads.
// Ps LDS: per-wave P tile [16][72 pad] for C-layout -> A-layout round trip.
__global__ __launch_bounds__(256) void flash_attn(const bf16* __restrict__ qkv,
                                                  bf16* __restrict__ ctx) {
    const int qt0  = blockIdx.x * 64;
    const int h    = blockIdx.y;
    const int kh   = h >> 2;
    const int t    = threadIdx.x;
    const int wave = t >> 6, lane = t & 63;
    const int quad = lane >> 4, l15 = lane & 15;

    __shared__ bf16 Ks[16 * 64 * 8];   // 8192 elems
    __shared__ bf16 Vt[128 * 72];      // 9216 elems
    __shared__ bf16 Ps[4 * 16 * 72];   // 4608 elems

    const bf16* Qb = qkv + h * HD;
    const bf16* Kb = qkv + K_OFF + kh * HD;
    const bf16* Vb = qkv + V_OFF + kh * HD;

    // Q fragments (A-operand: m = lane&15, k = quad*8+j), kept in registers
    const int qrow_a = qt0 + wave * 16 + l15;
    bf16x8 qf[4];
#pragma unroll
    for (int kk = 0; kk < 4; ++kk)
        qf[kk] = *reinterpret_cast<const bf16x8*>(Qb + (size_t)qrow_a * QKV_N + kk * 32 + quad * 8);

    float m_i[4], l_i[4];
    f32x4 o_acc[8];
#pragma unroll
    for (int r = 0; r < 4; ++r) { m_i[r] = -1e30f; l_i[r] = 0.f; }
#pragma unroll
    for (int dt = 0; dt < 8; ++dt) o_acc[dt] = (f32x4){0.f, 0.f, 0.f, 0.f};

    const int myrow = qt0 + wave * 16 + quad * 4;  // + r gives this lane's C-layout rows
    bf16* PsW = Ps + wave * (16 * 72);

    for (int kv0 = 0; kv0 < qt0 + 64; kv0 += 64) {
        __syncthreads();
        // stage K tile: plane cd = it*4+wave (wave-uniform), lane = kv row
#pragma unroll
        for (int it = 0; it < 4; ++it) {
            const int cd = it * 4 + wave;
            gload16(Kb + (size_t)(kv0 + lane) * QKV_N + cd * 8,
                    Ks + it * 2048 + wave * 512);
        }
        // stage V transposed: lane = kv row n, read 8 d's, scatter to Vt[d][n]
        {
            const int n  = t & 63;
            const int dg = t >> 6;
#pragma unroll
            for (int it = 0; it < 4; ++it) {
                const int d0 = (it * 4 + dg) * 8;
                bf16x8 v = *reinterpret_cast<const bf16x8*>(Vb + (size_t)(kv0 + n) * QKV_N + d0);
#pragma unroll
                for (int e = 0; e < 8; ++e) Vt[(d0 + e) * 72 + n] = v[e];
            }
        }
        __syncthreads();

        // S = Q K^T  (16 q-rows x 64 kv-cols per wave)
        float sv[4][4];
#pragma unroll
        for (int j = 0; j < 4; ++j) {
            f32x4 s = (f32x4){0.f, 0.f, 0.f, 0.f};
#pragma unroll
            for (int kk = 0; kk < 4; ++kk) {
                const int cd = kk * 4 + quad;
                bf16x8 kf = *reinterpret_cast<const bf16x8*>(&Ks[cd * 512 + (j * 16 + l15) * 8]);
                s = __builtin_amdgcn_mfma_f32_16x16x32_bf16(qf[kk], kf, s, 0, 0, 0);
            }
#pragma unroll
            for (int r = 0; r < 4; ++r) {
                const float x = s[r] * ATT_SCALE;
                sv[j][r] = ((kv0 + j * 16 + l15) <= (myrow + r)) ? x : -1e30f;
            }
        }

        // online softmax (rows live on quad's 16 lanes; reduce over lane&15)
        float al[4];
#pragma unroll
        for (int r = 0; r < 4; ++r) {
            float mt = fmaxf(fmaxf(sv[0][r], sv[1][r]), fmaxf(sv[2][r], sv[3][r]));
#pragma unroll
            for (int off = 1; off < 16; off <<= 1) mt = fmaxf(mt, __shfl_xor(mt, off));
            const float mn = fmaxf(m_i[r], mt);
            al[r] = __expf(m_i[r] - mn);
            m_i[r] = mn;
            float rs = 0.f;
#pragma unroll
            for (int j = 0; j < 4; ++j) {
                const float p = __expf(sv[j][r] - mn);
                rs += p;
                PsW[(quad * 4 + r) * 72 + j * 16 + l15] = (bf16)p;  // C-layout -> LDS
            }
#pragma unroll
            for (int off = 1; off < 16; off <<= 1) rs += __shfl_xor(rs, off);
            l_i[r] = l_i[r] * al[r] + rs;
        }

        // rescale O accumulator
#pragma unroll
        for (int dt = 0; dt < 8; ++dt) {
            o_acc[dt][0] *= al[0]; o_acc[dt][1] *= al[1];
            o_acc[dt][2] *= al[2]; o_acc[dt][3] *= al[3];
        }

        // P in A-layout from LDS, then PV MFMAs (K-dim = 64 kv = 2 chunks of 32)
        bf16x8 pa[2];
        pa[0] = *reinterpret_cast<const bf16x8*>(&PsW[l15 * 72 + quad * 8]);
        pa[1] = *reinterpret_cast<const bf16x8*>(&PsW[l15 * 72 + 32 + quad * 8]);
#pragma unroll
        for (int dt = 0; dt < 8; ++dt) {
#pragma unroll
            for (int c = 0; c < 2; ++c) {
                bf16x8 vb = *reinterpret_cast<const bf16x8*>(&Vt[(dt * 16 + l15) * 72 + c * 32 + quad * 8]);
                o_acc[dt] = __builtin_amdgcn_mfma_f32_16x16x32_bf16(pa[c], vb, o_acc[dt], 0, 0, 0);
            }
        }
    }

    // epilogue: ctx[row][h*128 + d] = O / l
#pragma unroll
    for (int dt = 0; dt < 8; ++dt)
#pragma unroll
        for (int r = 0; r < 4; ++r)
            ctx[(size_t)(myrow + r) * DMODEL + h * HD + dt * 16 + l15] =
                (bf16)(o_acc[dt][r] / l_i[r]);
}

// ---------------- launch ----------------
extern "C" void kernel_launch(void* const* d_in, const int* in_sizes, int n_in,
                              void* d_out, int out_size, void* d_ws, size_t ws_size,
                              hipStream_t stream) {
    const float* x    = (const float*)d_in[0];
    const float* cosT = (const float*)d_in[1];
    const float* sinT = (const float*)d_in[2];
    const float* Wq   = (const float*)d_in[3];
    const float* Wk   = (const float*)d_in[4];
    const float* Wv   = (const float*)d_in[5];
    const float* Wo   = (const float*)d_in[6];
    float* out = (float*)d_out;

    // workspace layout (bf16 elems): xb | Wqkv | Wo | QKV | ctx   (~136 MiB)
    bf16* xb   = (bf16*)d_ws;
    bf16* Wqkv = xb   + (size_t)S_LEN * DMODEL;        // 6144 x 4096
    bf16* Wob  = Wqkv + (size_t)QKV_N * DMODEL;        // 4096 x 4096
    bf16* QKV  = Wob  + (size_t)DMODEL * DMODEL;       // 2048 x 6144
    bf16* ctx  = QKV  + (size_t)S_LEN * QKV_N;         // 2048 x 4096

    // casts fp32 -> bf16 (Wq/Wk/Wv packed row-wise into one 6144x4096 block)
    cast_f32_bf16<<<(S_LEN * DMODEL / 4 + 255) / 256, 256, 0, stream>>>(x, xb, S_LEN * DMODEL / 4);
    cast_f32_bf16<<<(DMODEL * DMODEL / 4 + 255) / 256, 256, 0, stream>>>(Wq, Wqkv, DMODEL * DMODEL / 4);
    cast_f32_bf16<<<(1024 * DMODEL / 4 + 255) / 256, 256, 0, stream>>>(
        Wk, Wqkv + (size_t)4096 * DMODEL, 1024 * DMODEL / 4);
    cast_f32_bf16<<<(1024 * DMODEL / 4 + 255) / 256, 256, 0, stream>>>(
        Wv, Wqkv + (size_t)5120 * DMODEL, 1024 * DMODEL / 4);
    cast_f32_bf16<<<(DMODEL * DMODEL / 4 + 255) / 256, 256, 0, stream>>>(Wo, Wob, DMODEL * DMODEL / 4);

    // fused QKV projection: (2048 x 4096) @ (6144 x 4096)^T -> 2048 x 6144 bf16
    gemm_bt<bf16><<<dim3(QKV_N / 128, S_LEN / 128), 256, 0, stream>>>(
        xb, Wqkv, QKV, S_LEN, QKV_N, DMODEL, QKV_N);

    // RoPE on Q (heads 0..31) and K (heads 32..39 of the packed buffer)
    rope_kernel<<<dim3(10, S_LEN), 256, 0, stream>>>(QKV, cosT, sinT);

    // flash attention -> ctx bf16 (2048 x 4096)
    flash_attn<<<dim3(S_LEN / 64, 32), 256, 0, stream>>>(QKV, ctx);

    // output projection: (2048 x 4096) @ (4096 x 4096)^T -> fp32 out
    gemm_bt<float><<<dim3(DMODEL / 128, S_LEN / 128), 256, 0, stream>>>(
        ctx, Wob, out, S_LEN, DMODEL, DMODEL, DMODEL);
}

// Round 2
// 558.854 us; speedup vs baseline: 1.3245x; 1.3245x over previous
//
#include <hip/hip_runtime.h>

// GroupedQueryAttention: B=1, S=2048, D_IN=D_OUT=4096, NH=32, NKV=8, HD=128, causal.
// Pipeline: cast->bf16, fused QKV GEMM (MFMA), RoPE, V-transpose, flash attention, out GEMM.

typedef __bf16 bf16;
typedef __bf16 bf16x4 __attribute__((ext_vector_type(4)));
typedef __bf16 bf16x8 __attribute__((ext_vector_type(8)));
typedef float  f32x4  __attribute__((ext_vector_type(4)));

#define S_LEN   2048
#define DMODEL  4096
#define QKV_N   6144      // 4096 Q + 1024 K + 1024 V
#define K_OFF   4096
#define V_OFF   5120
#define HD      128
#define ATT_SCALE 0.08838834764831845f  // 1/sqrt(128)

// async global->LDS, 16B per lane; LDS dest is wave-uniform base + lane*16
__device__ __forceinline__ void gload16(const bf16* g, bf16* l) {
    __builtin_amdgcn_global_load_lds(
        (__attribute__((address_space(1))) void*)(g),
        (__attribute__((address_space(3))) void*)(l),
        16, 0, 0);
}

// ---------------- cast fp32 -> bf16, float4 vectorized ----------------
__global__ __launch_bounds__(256) void cast_f32_bf16(const float* __restrict__ in,
                                                     bf16* __restrict__ out, int n4) {
    int i = blockIdx.x * 256 + threadIdx.x;
    if (i >= n4) return;
    float4 v = reinterpret_cast<const float4*>(in)[i];
    bf16x4 o;
    o[0] = (bf16)v.x; o[1] = (bf16)v.y; o[2] = (bf16)v.z; o[3] = (bf16)v.w;
    reinterpret_cast<bf16x4*>(out)[i] = o;
}

// ---------------- GEMM: C[M,N] = A[M,K] * B[N,K]^T  (both row-major, K contig) ------
// m97 structure: 128x128 tile, BK=32, 4 waves, each wave 64x64 (4x4 of 16x16x32 MFMA)
template <typename OutT>
__global__ __launch_bounds__(256) void gemm_bt(const bf16* __restrict__ A,
                                               const bf16* __restrict__ B,
                                               OutT* __restrict__ C,
                                               int M, int N, int K, int ldc) {
    __shared__ bf16 As[128 * 32];
    __shared__ bf16 Bs[128 * 32];
    const int t    = threadIdx.x;
    const int wave = t >> 6, lane = t & 63;
    const int quad = lane >> 4, l15 = lane & 15;
    const int wm = (wave >> 1) * 64, wn = (wave & 1) * 64;
    const int bm = blockIdx.y * 128, bn = blockIdx.x * 128;

    f32x4 acc[4][4];
#pragma unroll
    for (int i = 0; i < 4; ++i)
#pragma unroll
        for (int j = 0; j < 4; ++j) acc[i][j] = (f32x4){0.f, 0.f, 0.f, 0.f};

    const int soff  = t * 8;
    const int arow0 = soff >> 5;
    const int acol  = soff & 31;

    for (int k0 = 0; k0 < K; k0 += 32) {
        __syncthreads();
#pragma unroll
        for (int it = 0; it < 2; ++it) {
            gload16(A + (size_t)(bm + arow0 + it * 64) * K + k0 + acol,
                    As + it * 2048 + wave * 512);
            gload16(B + (size_t)(bn + arow0 + it * 64) * K + k0 + acol,
                    Bs + it * 2048 + wave * 512);
        }
        __syncthreads();

        bf16x8 af[4], bfb[4];
#pragma unroll
        for (int i = 0; i < 4; ++i)
            af[i] = *reinterpret_cast<const bf16x8*>(&As[(wm + i * 16 + l15) * 32 + quad * 8]);
#pragma unroll
        for (int j = 0; j < 4; ++j)
            bfb[j] = *reinterpret_cast<const bf16x8*>(&Bs[(wn + j * 16 + l15) * 32 + quad * 8]);
#pragma unroll
        for (int i = 0; i < 4; ++i)
#pragma unroll
            for (int j = 0; j < 4; ++j)
                acc[i][j] = __builtin_amdgcn_mfma_f32_16x16x32_bf16(af[i], bfb[j], acc[i][j], 0, 0, 0);
    }

    // C/D layout: col = lane&15, row = quad*4 + reg
#pragma unroll
    for (int i = 0; i < 4; ++i) {
        const int m0 = bm + wm + i * 16 + quad * 4;
#pragma unroll
        for (int j = 0; j < 4; ++j) {
            const int n = bn + wn + j * 16 + l15;
#pragma unroll
            for (int r = 0; r < 4; ++r)
                C[(size_t)(m0 + r) * ldc + n] = (OutT)acc[i][j][r];
        }
    }
}

// ---------------- RoPE on Q (32 heads) + K (8 heads) in the fused QKV buffer --------
__global__ __launch_bounds__(256) void rope_kernel(bf16* __restrict__ qkv,
                                                   const float* __restrict__ cosT,
                                                   const float* __restrict__ sinT) {
    const int col = blockIdx.x * 256 + threadIdx.x;  // 0 .. 40*64-1
    if (col >= 40 * 64) return;
    const int row  = blockIdx.y;
    const int head = col >> 6, d = col & 63;
    const size_t base = (size_t)row * QKV_N + head * 128 + d;
    const float x1 = (float)qkv[base];
    const float x2 = (float)qkv[base + 64];
    const float c  = cosT[row * 128 + d];
    const float s  = sinT[row * 128 + d];
    qkv[base]      = (bf16)(x1 * c - x2 * s);
    qkv[base + 64] = (bf16)(x2 * c + x1 * s);
}

// ---------------- V transpose: QKV V-region (2048 x 1024) -> Vt (1024 x 2048) -------
__global__ __launch_bounds__(256) void transpose_v(const bf16* __restrict__ qkv,
                                                   bf16* __restrict__ vt) {
    __shared__ bf16 T[64][72];
    const int c0 = blockIdx.x * 64;   // V column tile (0..1023)
    const int s0 = blockIdx.y * 64;   // sequence tile
    const int t  = threadIdx.x;
#pragma unroll
    for (int it = 0; it < 2; ++it) {
        const int sl = (t >> 3) + it * 32;
        const int c8 = (t & 7) * 8;
        bf16x8 v = *reinterpret_cast<const bf16x8*>(
            qkv + (size_t)(s0 + sl) * QKV_N + V_OFF + c0 + c8);
        *reinterpret_cast<bf16x8*>(&T[sl][c8]) = v;
    }
    __syncthreads();
#pragma unroll
    for (int it = 0; it < 2; ++it) {
        const int cl = (t >> 3) + it * 32;
        const int s8 = (t & 7) * 8;
        bf16x8 o;
#pragma unroll
        for (int e = 0; e < 8; ++e) o[e] = T[s8 + e][cl];
        *reinterpret_cast<bf16x8*>(vt + (size_t)(c0 + cl) * S_LEN + s0 + s8) = o;
    }
}

// ---------------- flash attention, causal, GQA group=4 ----------------
// 512 thr = 8 waves; BQ=128 (16 q-rows/wave), BKV=64, HD=128.
// Ks LDS: row-major 64x128, chunk c (16B) of row r holds global chunk c^(r&15)
//   (XOR swizzle) -> coalesced gload16 staging AND uniform-bank ds_read_b128.
// Vs LDS: from pre-transposed Vt, 128 rows x 64 kv, chunk c of row d holds c^(d&7).
// Ps LDS: per-wave P tile [16][72 pad] for C-layout -> A-layout round trip.
__global__ __launch_bounds__(512) void flash_attn(const bf16* __restrict__ qkv,
                                                  const bf16* __restrict__ vt,
                                                  bf16* __restrict__ ctx) {
    const int blk   = blockIdx.x;
    const int qtile = 15 - (blk >> 5);       // longest blocks dispatched first
    const int h     = blk & 31;
    const int kh    = h >> 2;
    const int q0    = qtile * 128;
    const int t     = threadIdx.x;
    const int wave  = t >> 6, lane = t & 63;
    const int quad  = lane >> 4, l15 = lane & 15;

    __shared__ bf16 Ks[64 * 128];    // 16 KB
    __shared__ bf16 Vs[128 * 64];    // 16 KB
    __shared__ bf16 Ps[8 * 16 * 72]; // 18 KB

    const bf16* Qb  = qkv + h * HD;
    const bf16* Kb  = qkv + K_OFF + kh * HD;
    const bf16* Vth = vt + (size_t)kh * HD * S_LEN;

    // Q fragments (A-operand: m = lane&15, k = quad*8+j), once per block
    const int qrow_a = q0 + wave * 16 + l15;
    bf16x8 qf[4];
#pragma unroll
    for (int kk = 0; kk < 4; ++kk)
        qf[kk] = *reinterpret_cast<const bf16x8*>(
            Qb + (size_t)qrow_a * QKV_N + kk * 32 + quad * 8);

    float m_i[4], l_i[4];
    f32x4 o_acc[8];
#pragma unroll
    for (int r = 0; r < 4; ++r) { m_i[r] = -1e30f; l_i[r] = 0.f; }
#pragma unroll
    for (int dt = 0; dt < 8; ++dt) o_acc[dt] = (f32x4){0.f, 0.f, 0.f, 0.f};

    const int myrow = q0 + wave * 16 + quad * 4;
    bf16* PsW = Ps + wave * (16 * 72);

    for (int kv0 = 0; kv0 < q0 + 128; kv0 += 64) {
        __syncthreads();
        // stage K tile (64 rows x 128 d), coalesced rows, XOR-swizzled chunks
#pragma unroll
        for (int it = 0; it < 2; ++it) {
            const int rb = wave * 8 + it * 4;
            const int r  = rb + (lane >> 4);
            const int cg = (lane & 15) ^ (r & 15);
            gload16(Kb + (size_t)(kv0 + r) * QKV_N + cg * 8, Ks + rb * 128);
        }
        // stage V tile (128 d-rows x 64 kv) from pre-transposed Vt
#pragma unroll
        for (int it = 0; it < 2; ++it) {
            const int db = wave * 16 + it * 8;
            const int d  = db + (lane >> 3);
            const int cg = (lane & 7) ^ (d & 7);
            gload16(Vth + (size_t)d * S_LEN + kv0 + cg * 8, Vs + db * 64);
        }
        __syncthreads();

        // S = Q K^T  (16 q-rows x 64 kv-cols per wave)
        float sv[4][4];
        const bool need_mask = (kv0 + 63) > q0;  // block-uniform
#pragma unroll
        for (int j = 0; j < 4; ++j) {
            f32x4 s = (f32x4){0.f, 0.f, 0.f, 0.f};
#pragma unroll
            for (int kk = 0; kk < 4; ++kk) {
                const int cd = kk * 4 + quad;
                bf16x8 kf = *reinterpret_cast<const bf16x8*>(
                    &Ks[(j * 16 + l15) * 128 + ((cd ^ l15) & 15) * 8]);
                s = __builtin_amdgcn_mfma_f32_16x16x32_bf16(qf[kk], kf, s, 0, 0, 0);
            }
            if (need_mask) {
#pragma unroll
                for (int r = 0; r < 4; ++r)
                    sv[j][r] = ((kv0 + j * 16 + l15) <= (myrow + r))
                                   ? s[r] * ATT_SCALE : -1e30f;
            } else {
#pragma unroll
                for (int r = 0; r < 4; ++r) sv[j][r] = s[r] * ATT_SCALE;
            }
        }

        // online softmax (reduce over the 16 lanes of l15)
        float al[4];
#pragma unroll
        for (int r = 0; r < 4; ++r) {
            float mt = fmaxf(fmaxf(sv[0][r], sv[1][r]), fmaxf(sv[2][r], sv[3][r]));
#pragma unroll
            for (int off = 1; off < 16; off <<= 1) mt = fmaxf(mt, __shfl_xor(mt, off));
            const float mn = fmaxf(m_i[r], mt);
            al[r] = __expf(m_i[r] - mn);
            m_i[r] = mn;
            float rs = 0.f;
#pragma unroll
            for (int j = 0; j < 4; ++j) {
                const float p = __expf(sv[j][r] - mn);
                rs += p;
                PsW[(quad * 4 + r) * 72 + j * 16 + l15] = (bf16)p;  // C-layout -> LDS
            }
#pragma unroll
            for (int off = 1; off < 16; off <<= 1) rs += __shfl_xor(rs, off);
            l_i[r] = l_i[r] * al[r] + rs;
        }

        // rescale O accumulator
#pragma unroll
        for (int dt = 0; dt < 8; ++dt) {
            o_acc[dt][0] *= al[0]; o_acc[dt][1] *= al[1];
            o_acc[dt][2] *= al[2]; o_acc[dt][3] *= al[3];
        }

        // P back in A-layout; PV MFMAs (K-dim = 64 kv = 2 chunks of 32)
        bf16x8 pa[2];
        pa[0] = *reinterpret_cast<const bf16x8*>(&PsW[l15 * 72 + quad * 8]);
        pa[1] = *reinterpret_cast<const bf16x8*>(&PsW[l15 * 72 + 32 + quad * 8]);
#pragma unroll
        for (int dt = 0; dt < 8; ++dt) {
#pragma unroll
            for (int c = 0; c < 2; ++c) {
                const int ck = c * 4 + quad;
                bf16x8 vb = *reinterpret_cast<const bf16x8*>(
                    &Vs[(dt * 16 + l15) * 64 + ((ck ^ (l15 & 7)) & 7) * 8]);
                o_acc[dt] = __builtin_amdgcn_mfma_f32_16x16x32_bf16(pa[c], vb, o_acc[dt], 0, 0, 0);
            }
        }
    }

    // epilogue: ctx[row][h*128 + d] = O / l
#pragma unroll
    for (int dt = 0; dt < 8; ++dt)
#pragma unroll
        for (int r = 0; r < 4; ++r)
            ctx[(size_t)(myrow + r) * DMODEL + h * HD + dt * 16 + l15] =
                (bf16)(o_acc[dt][r] / l_i[r]);
}

// ---------------- launch ----------------
extern "C" void kernel_launch(void* const* d_in, const int* in_sizes, int n_in,
                              void* d_out, int out_size, void* d_ws, size_t ws_size,
                              hipStream_t stream) {
    const float* x    = (const float*)d_in[0];
    const float* cosT = (const float*)d_in[1];
    const float* sinT = (const float*)d_in[2];
    const float* Wq   = (const float*)d_in[3];
    const float* Wk   = (const float*)d_in[4];
    const float* Wv   = (const float*)d_in[5];
    const float* Wo   = (const float*)d_in[6];
    float* out = (float*)d_out;

    // workspace layout (bf16 elems): xb | Wqkv | Wo | QKV | ctx | Vt  (~147 MiB)
    bf16* xb   = (bf16*)d_ws;
    bf16* Wqkv = xb   + (size_t)S_LEN * DMODEL;        // 6144 x 4096
    bf16* Wob  = Wqkv + (size_t)QKV_N * DMODEL;        // 4096 x 4096
    bf16* QKV  = Wob  + (size_t)DMODEL * DMODEL;       // 2048 x 6144
    bf16* ctx  = QKV  + (size_t)S_LEN * QKV_N;         // 2048 x 4096
    bf16* Vt   = ctx  + (size_t)S_LEN * DMODEL;        // 1024 x 2048

    cast_f32_bf16<<<(S_LEN * DMODEL / 4 + 255) / 256, 256, 0, stream>>>(x, xb, S_LEN * DMODEL / 4);
    cast_f32_bf16<<<(DMODEL * DMODEL / 4 + 255) / 256, 256, 0, stream>>>(Wq, Wqkv, DMODEL * DMODEL / 4);
    cast_f32_bf16<<<(1024 * DMODEL / 4 + 255) / 256, 256, 0, stream>>>(
        Wk, Wqkv + (size_t)4096 * DMODEL, 1024 * DMODEL / 4);
    cast_f32_bf16<<<(1024 * DMODEL / 4 + 255) / 256, 256, 0, stream>>>(
        Wv, Wqkv + (size_t)5120 * DMODEL, 1024 * DMODEL / 4);
    cast_f32_bf16<<<(DMODEL * DMODEL / 4 + 255) / 256, 256, 0, stream>>>(Wo, Wob, DMODEL * DMODEL / 4);

    // fused QKV projection: (2048 x 4096) @ (6144 x 4096)^T -> 2048 x 6144 bf16
    gemm_bt<bf16><<<dim3(QKV_N / 128, S_LEN / 128), 256, 0, stream>>>(
        xb, Wqkv, QKV, S_LEN, QKV_N, DMODEL, QKV_N);

    // RoPE on Q (heads 0..31) and K (heads 32..39 of the packed buffer)
    rope_kernel<<<dim3(10, S_LEN), 256, 0, stream>>>(QKV, cosT, sinT);

    // V transpose for coalesced flash staging
    transpose_v<<<dim3(16, 32), 256, 0, stream>>>(QKV, Vt);

    // flash attention -> ctx bf16 (2048 x 4096); longest-first 1D grid
    flash_attn<<<dim3(16 * 32), 512, 0, stream>>>(QKV, Vt, ctx);

    // output projection: (2048 x 4096) @ (4096 x 4096)^T -> fp32 out
    gemm_bt<float><<<dim3(DMODEL / 128, S_LEN / 128), 256, 0, stream>>>(
        ctx, Wob, out, S_LEN, DMODEL, DMODEL, DMODEL);
}